// Round 1
// baseline (156.177 us; speedup 1.0000x reference)
//
#include <hip/hip_runtime.h>
#include <stdint.h>

// Radius-graph edge list, B=4, N=2048, cutoff 5.0.
// Output [2, B*P] int32: compacted valid edges (ascending flat index), -1 pad.
// Pipeline: fill(-1) -> per-block count -> single-block scan -> ranked write.

namespace {
constexpr int kB = 4;
constexpr int kN = 2048;
constexpr int kP = kN * (kN - 1) / 2;              // 2096128
constexpr long long kTotal = (long long)kB * kP;   // 8384512
constexpr int kBlock = 256;
constexpr int kItems = 8;
constexpr int kChunk = kBlock * kItems;            // 2048
constexpr int kNBlk = (int)(kTotal / kChunk);      // 4094 (exact, no tail)
constexpr float kCut2 = 25.0f;                     // 5.0^2
constexpr int kScanPer = (kNBlk + kBlock - 1) / kBlock; // 16
}  // namespace

// p in [0,P) -> (i,j), i<j, triu row-major order. Closed-form sqrt guess +
// exact integer fixup (robust to sqrt rounding). C(i) = i*(4095-i)/2.
__device__ __forceinline__ void decode_pair(int p, int& i, int& j) {
  float t = sqrtf((float)(16769025 - 8 * p));      // disc = 4095^2 - 8p, < 2^24 exact
  int ii = (int)((4095.0f - t) * 0.5f);
  ii = ii < 0 ? 0 : (ii > kN - 2 ? kN - 2 : ii);
  while (ii > 0 && (ii * (4095 - ii)) / 2 > p) --ii;
  while (ii < kN - 2 && ((ii + 1) * (4094 - ii)) / 2 <= p) ++ii;
  i = ii;
  j = ii + 1 + (p - (ii * (4095 - ii)) / 2);
}

__device__ __forceinline__ bool edge_test(const float* __restrict__ x, int f,
                                          int& b, int& i, int& j) {
  b = (int)((unsigned)f / (unsigned)kP);           // magic-mul div by constant
  int p = f - b * kP;
  decode_pair(p, i, j);
  const float* xb = x + (size_t)b * kN * 3;
  float dx = xb[3 * i + 0] - xb[3 * j + 0];
  float dy = xb[3 * i + 1] - xb[3 * j + 1];
  float dz = xb[3 * i + 2] - xb[3 * j + 2];
  return dx * dx + dy * dy + dz * dz <= kCut2;
}

__global__ __launch_bounds__(kBlock) void fill_kernel(int4* __restrict__ out, int n4) {
  int idx = blockIdx.x * kBlock + threadIdx.x;
  if (idx < n4) out[idx] = make_int4(-1, -1, -1, -1);
}

__global__ __launch_bounds__(kBlock) void count_kernel(const float* __restrict__ x,
                                                       uint32_t* __restrict__ counts) {
  const int t = threadIdx.x;
  const int base = blockIdx.x * kChunk;
  int cnt = 0;
  for (int k = 0; k < kItems; ++k) {
    int b, i, j;
    // item-major: lane index = consecutive flat index -> coalesced j-gather
    if (edge_test(x, base + k * kBlock + t, b, i, j)) ++cnt;
  }
  __shared__ int wsum[kBlock / 64];
  for (int off = 32; off > 0; off >>= 1) cnt += __shfl_down(cnt, off, 64);
  if ((t & 63) == 0) wsum[t >> 6] = cnt;
  __syncthreads();
  if (t == 0) counts[blockIdx.x] = wsum[0] + wsum[1] + wsum[2] + wsum[3];
}

__global__ __launch_bounds__(kBlock) void scan_kernel(const uint32_t* __restrict__ counts,
                                                      uint32_t* __restrict__ offsets) {
  __shared__ uint32_t s[kBlock];
  const int t = threadIdx.x;
  uint32_t loc[kScanPer];
  uint32_t sum = 0;
  for (int k = 0; k < kScanPer; ++k) {
    int idx = t * kScanPer + k;
    uint32_t c = (idx < kNBlk) ? counts[idx] : 0u;
    loc[k] = sum;          // thread-local exclusive prefix
    sum += c;
  }
  s[t] = sum;
  __syncthreads();
  // Hillis-Steele inclusive scan over 256 thread sums
  for (int off = 1; off < kBlock; off <<= 1) {
    uint32_t u = (t >= off) ? s[t - off] : 0u;
    __syncthreads();
    if (t >= off) s[t] += u;
    __syncthreads();
  }
  uint32_t base = (t == 0) ? 0u : s[t - 1];
  for (int k = 0; k < kScanPer; ++k) {
    int idx = t * kScanPer + k;
    if (idx < kNBlk) offsets[idx] = base + loc[k];
  }
}

__global__ __launch_bounds__(kBlock) void write_kernel(const float* __restrict__ x,
                                                       const uint32_t* __restrict__ offsets,
                                                       int* __restrict__ out) {
  const int t = threadIdx.x;
  const int wave = t >> 6, lane = t & 63;
  const int base = blockIdx.x * kChunk;
  __shared__ uint32_t slot[kItems * 4];  // per (item, wave) popcounts -> exclusive scan

  unsigned long long masks[kItems];
  int bi[kItems], ii[kItems], jj[kItems];
  bool fl[kItems];
  for (int k = 0; k < kItems; ++k) {
    fl[k] = edge_test(x, base + k * kBlock + t, bi[k], ii[k], jj[k]);
    masks[k] = __ballot(fl[k]);
    if (lane == 0) slot[k * 4 + wave] = (uint32_t)__popcll(masks[k]);
  }
  __syncthreads();
  if (t == 0) {  // serial exclusive scan of 32 entries: trivial
    uint32_t run = 0;
    for (int sIdx = 0; sIdx < kItems * 4; ++sIdx) {
      uint32_t c = slot[sIdx];
      slot[sIdx] = run;
      run += c;
    }
  }
  __syncthreads();
  const uint32_t blockBase = offsets[blockIdx.x];
  for (int k = 0; k < kItems; ++k) {
    if (fl[k]) {
      uint32_t pos = blockBase + slot[k * 4 + wave] +
                     (uint32_t)__popcll(masks[k] & ((1ULL << lane) - 1ULL));
      out[pos] = bi[k] * kN + ii[k];
      out[(size_t)kTotal + pos] = bi[k] * kN + jj[k];
    }
  }
}

extern "C" void kernel_launch(void* const* d_in, const int* in_sizes, int n_in,
                              void* d_out, int out_size, void* d_ws, size_t ws_size,
                              hipStream_t stream) {
  const float* x = (const float*)d_in[0];
  int* out = (int*)d_out;
  uint32_t* counts = (uint32_t*)d_ws;
  uint32_t* offsets = counts + kNBlk;

  const int n4 = out_size / 4;  // out_size = 2*B*P, divisible by 4
  hipLaunchKernelGGL(fill_kernel, dim3((n4 + kBlock - 1) / kBlock), dim3(kBlock), 0,
                     stream, (int4*)d_out, n4);
  hipLaunchKernelGGL(count_kernel, dim3(kNBlk), dim3(kBlock), 0, stream, x, counts);
  hipLaunchKernelGGL(scan_kernel, dim3(1), dim3(kBlock), 0, stream, counts, offsets);
  hipLaunchKernelGGL(write_kernel, dim3(kNBlk), dim3(kBlock), 0, stream, x, offsets, out);
}

// Round 2
// 114.478 us; speedup vs baseline: 1.3643x; 1.3643x over previous
//
#include <hip/hip_runtime.h>
#include <stdint.h>

// Radius-graph edge list, B=4, N=2048, cutoff 5.0.
// Output [2, B*P] int32: compacted valid edges (ascending flat index), -1 pad.
// Pipeline (3 kernels):
//   pass1: fill own out-slice with -1 + edge tests (once) + per-block count
//          + compacted (gi,gj) stash into ws
//   scan : single-block exclusive scan of 4094 block counts (uint4 loads)
//   scatter: copy stashed edges to final offsets (recompute fallback if a
//            block exceeded stash capacity — practically never, but exact)

namespace {
constexpr int kB = 4;
constexpr int kN = 2048;
constexpr int kP = kN * (kN - 1) / 2;              // 2096128
constexpr long long kTotal = (long long)kB * kP;   // 8384512
constexpr int kBlock = 256;
constexpr int kItems = 8;
constexpr int kChunk = kBlock * kItems;            // 2048
constexpr int kNBlk = (int)(kTotal / kChunk);      // 4094 (exact, no tail)
constexpr float kCut2 = 25.0f;                     // 5.0^2
constexpr int kScanPer = 16;                       // 256*16 = 4096 >= 4094
constexpr int kCap = 128;                          // stash slots per block
}  // namespace

// p in [0,P) -> (i,j), i<j, triu row-major. Closed-form sqrt guess + exact
// integer fixup. C(i) = i*(4095-i)/2. disc < 2^24 so float sqrt is tight.
__device__ __forceinline__ void decode_pair(int p, int& i, int& j) {
  float t = sqrtf((float)(16769025 - 8 * p));
  int ii = (int)((4095.0f - t) * 0.5f);
  ii = ii < 0 ? 0 : (ii > kN - 2 ? kN - 2 : ii);
  while (ii > 0 && (ii * (4095 - ii)) / 2 > p) --ii;
  while (ii < kN - 2 && ((ii + 1) * (4094 - ii)) / 2 <= p) ++ii;
  i = ii;
  j = ii + 1 + (p - (ii * (4095 - ii)) / 2);
}

__device__ __forceinline__ bool pair_test(const float* __restrict__ x, int b, int p,
                                          int& gi, int& gj) {
  int i, j;
  decode_pair(p, i, j);
  const float* xb = x + (size_t)b * kN * 3;
  float dx = xb[3 * i + 0] - xb[3 * j + 0];
  float dy = xb[3 * i + 1] - xb[3 * j + 1];
  float dz = xb[3 * i + 2] - xb[3 * j + 2];
  gi = b * kN + i;
  gj = b * kN + j;
  return dx * dx + dy * dy + dz * dz <= kCut2;
}

__global__ __launch_bounds__(kBlock) void pass1_kernel(const float* __restrict__ x,
                                                       uint32_t* __restrict__ counts,
                                                       int2* __restrict__ stash,
                                                       int* __restrict__ out) {
  const int t = threadIdx.x;
  const int wave = t >> 6, lane = t & 63;
  const int bid = blockIdx.x;
  const int base = bid * kChunk;

  // Fill this block's slice of both output rows with -1 (2048 ints each).
  {
    const int4 m1 = make_int4(-1, -1, -1, -1);
    int4* o0 = (int4*)out + (base >> 2);
    int4* o1 = (int4*)(out + kTotal) + (base >> 2);
    o0[t] = m1;
    o0[t + kBlock] = m1;
    o1[t] = m1;
    o1[t + kBlock] = m1;
  }
  if (bid == 0 && t < 2) counts[kNBlk + t] = 0;  // pad so scan can uint4-load

  // Block-uniform batch decode: a 2048-wide chunk crosses a batch boundary
  // at most once -> scalar div once + per-lane conditional subtract.
  const int bb0 = base / kP;
  const int p0 = base - bb0 * kP;

  __shared__ uint32_t slot[kItems * 4];
  unsigned long long masks[kItems];
  int gi[kItems], gj[kItems];
  bool fl[kItems];
  for (int k = 0; k < kItems; ++k) {
    int off = k * kBlock + t;  // item-major: lane = consecutive flat index
    int b = bb0, p = p0 + off;
    if (p >= kP) { p -= kP; ++b; }
    fl[k] = pair_test(x, b, p, gi[k], gj[k]);
    masks[k] = __ballot(fl[k]);
    if (lane == 0) slot[k * 4 + wave] = (uint32_t)__popcll(masks[k]);
  }
  __syncthreads();
  if (t == 0) {  // serial exclusive scan of 32 entries + total
    uint32_t run = 0;
    for (int s = 0; s < kItems * 4; ++s) {
      uint32_t c = slot[s];
      slot[s] = run;
      run += c;
    }
    counts[bid] = run;  // exact count (not capped)
  }
  __syncthreads();
  for (int k = 0; k < kItems; ++k) {
    if (fl[k]) {
      uint32_t pos = slot[k * 4 + wave] +
                     (uint32_t)__popcll(masks[k] & ((1ULL << lane) - 1ULL));
      if (pos < (uint32_t)kCap) stash[(size_t)bid * kCap + pos] = make_int2(gi[k], gj[k]);
    }
  }
}

__global__ __launch_bounds__(kBlock) void scan_kernel(const uint32_t* __restrict__ counts,
                                                      uint32_t* __restrict__ offsets) {
  __shared__ uint32_t s[kBlock];
  const int t = threadIdx.x;
  const uint4* c4 = (const uint4*)counts;  // [4096] incl. zero pad
  uint32_t loc[kScanPer];
  uint32_t sum = 0;
  for (int q = 0; q < 4; ++q) {
    uint4 c = c4[t * 4 + q];
    loc[q * 4 + 0] = sum; sum += c.x;
    loc[q * 4 + 1] = sum; sum += c.y;
    loc[q * 4 + 2] = sum; sum += c.z;
    loc[q * 4 + 3] = sum; sum += c.w;
  }
  s[t] = sum;
  __syncthreads();
  for (int off = 1; off < kBlock; off <<= 1) {
    uint32_t u = (t >= off) ? s[t - off] : 0u;
    __syncthreads();
    if (t >= off) s[t] += u;
    __syncthreads();
  }
  uint32_t base = (t == 0) ? 0u : s[t - 1];
  for (int k = 0; k < kScanPer; ++k) {
    int idx = t * kScanPer + k;
    if (idx < kNBlk) offsets[idx] = base + loc[k];
  }
}

__global__ __launch_bounds__(kBlock) void scatter_kernel(const float* __restrict__ x,
                                                         const uint32_t* __restrict__ counts,
                                                         const uint32_t* __restrict__ offsets,
                                                         const int2* __restrict__ stash,
                                                         int* __restrict__ out) {
  const int bid = blockIdx.x;
  const int t = threadIdx.x;
  const uint32_t cnt = counts[bid];
  if (cnt == 0) return;
  const uint32_t off = offsets[bid];
  if (cnt <= (uint32_t)kCap) {
    for (uint32_t e = t; e < cnt; e += kBlock) {
      int2 v = stash[(size_t)bid * kCap + e];
      out[off + e] = v.x;
      out[(size_t)kTotal + off + e] = v.y;
    }
    return;
  }
  // Overflow fallback (stash capacity exceeded): recompute this block's
  // edges with ballot ranks and write directly. Deterministic + exact.
  const int wave = t >> 6, lane = t & 63;
  const int base = bid * kChunk;
  const int bb0 = base / kP;
  const int p0 = base - bb0 * kP;
  __shared__ uint32_t slot[kItems * 4];
  unsigned long long masks[kItems];
  int gi[kItems], gj[kItems];
  bool fl[kItems];
  for (int k = 0; k < kItems; ++k) {
    int o = k * kBlock + t;
    int b = bb0, p = p0 + o;
    if (p >= kP) { p -= kP; ++b; }
    fl[k] = pair_test(x, b, p, gi[k], gj[k]);
    masks[k] = __ballot(fl[k]);
    if (lane == 0) slot[k * 4 + wave] = (uint32_t)__popcll(masks[k]);
  }
  __syncthreads();
  if (t == 0) {
    uint32_t run = 0;
    for (int s = 0; s < kItems * 4; ++s) {
      uint32_t c = slot[s];
      slot[s] = run;
      run += c;
    }
  }
  __syncthreads();
  for (int k = 0; k < kItems; ++k) {
    if (fl[k]) {
      uint32_t pos = off + slot[k * 4 + wave] +
                     (uint32_t)__popcll(masks[k] & ((1ULL << lane) - 1ULL));
      out[pos] = gi[k];
      out[(size_t)kTotal + pos] = gj[k];
    }
  }
}

extern "C" void kernel_launch(void* const* d_in, const int* in_sizes, int n_in,
                              void* d_out, int out_size, void* d_ws, size_t ws_size,
                              hipStream_t stream) {
  const float* x = (const float*)d_in[0];
  int* out = (int*)d_out;
  uint32_t* counts = (uint32_t*)d_ws;                 // [4096] (2 pad)
  uint32_t* offsets = counts + 4096;                  // [4094]
  int2* stash = (int2*)(offsets + 4096);              // [4094 * kCap]

  hipLaunchKernelGGL(pass1_kernel, dim3(kNBlk), dim3(kBlock), 0, stream, x, counts,
                     stash, out);
  hipLaunchKernelGGL(scan_kernel, dim3(1), dim3(kBlock), 0, stream, counts, offsets);
  hipLaunchKernelGGL(scatter_kernel, dim3(kNBlk), dim3(kBlock), 0, stream, x, counts,
                     offsets, stash, out);
}

// Round 3
// 92.266 us; speedup vs baseline: 1.6927x; 1.2407x over previous
//
#include <hip/hip_runtime.h>
#include <stdint.h>

// Radius-graph edge list, B=4, N=2048, cutoff 5.0.
// Output [2, B*P] int32: compacted valid edges (ascending flat index), -1 pad.
// Pipeline (3 kernels):
//   pass1: fill own out-slice with -1 + edge tests + per-block count + stash.
//          Pair decode is INCREMENTAL: one sqrt-decode per thread per block,
//          then walk (b,i,j) forward by +256 per item (rows are ~1e3 long, so
//          the walk loop runs ~1 iteration). float3 loads: 2 dwordx3 per pair.
//   scan : single-block exclusive scan of 4094 block counts (uint4 loads)
//   scatter: copy stashed edges to final offsets (recompute fallback if a
//            block exceeded stash capacity — practically never, but exact)

namespace {
constexpr int kB = 4;
constexpr int kN = 2048;
constexpr int kP = kN * (kN - 1) / 2;              // 2096128
constexpr long long kTotal = (long long)kB * kP;   // 8384512
constexpr int kBlock = 256;
constexpr int kItems = 8;
constexpr int kChunk = kBlock * kItems;            // 2048
constexpr int kNBlk = (int)(kTotal / kChunk);      // 4094 (exact, no tail)
constexpr float kCut2 = 25.0f;                     // 5.0^2
constexpr int kScanPer = 16;                       // 256*16 = 4096 >= 4094
constexpr int kCap = 128;                          // stash slots per block
}  // namespace

// p in [0,P) -> (i,j), i<j, triu row-major. Closed-form sqrt guess + exact
// integer fixup. C(i) = i*(4095-i)/2. disc < 2^24 so float sqrt is tight.
__device__ __forceinline__ void decode_pair(int p, int& i, int& j) {
  float t = sqrtf((float)(16769025 - 8 * p));
  int ii = (int)((4095.0f - t) * 0.5f);
  ii = ii < 0 ? 0 : (ii > kN - 2 ? kN - 2 : ii);
  while (ii > 0 && (ii * (4095 - ii)) / 2 > p) --ii;
  while (ii < kN - 2 && ((ii + 1) * (4094 - ii)) / 2 <= p) ++ii;
  i = ii;
  j = ii + 1 + (p - (ii * (4095 - ii)) / 2);
}

__device__ __forceinline__ bool pair_test(const float* __restrict__ x, int b, int p,
                                          int& gi, int& gj) {
  int i, j;
  decode_pair(p, i, j);
  const float* xb = x + (size_t)b * kN * 3;
  float dx = xb[3 * i + 0] - xb[3 * j + 0];
  float dy = xb[3 * i + 1] - xb[3 * j + 1];
  float dz = xb[3 * i + 2] - xb[3 * j + 2];
  gi = b * kN + i;
  gj = b * kN + j;
  return dx * dx + dy * dy + dz * dz <= kCut2;
}

__global__ __launch_bounds__(kBlock) void pass1_kernel(const float* __restrict__ x,
                                                       uint32_t* __restrict__ counts,
                                                       int2* __restrict__ stash,
                                                       int* __restrict__ out) {
  const int t = threadIdx.x;
  const int wave = t >> 6, lane = t & 63;
  const int bid = blockIdx.x;
  const int base = bid * kChunk;

  // Fill this block's slice of both output rows with -1 (2048 ints each).
  {
    const int4 m1 = make_int4(-1, -1, -1, -1);
    int4* o0 = (int4*)out + (base >> 2);
    int4* o1 = (int4*)(out + kTotal) + (base >> 2);
    o0[t] = m1;
    o0[t + kBlock] = m1;
    o1[t] = m1;
    o1[t + kBlock] = m1;
  }
  if (bid == 0 && t < 2) counts[kNBlk + t] = 0;  // pad so scan can uint4-load

  // One full decode per thread per block; then incremental row-walk.
  int b = base / kP;
  int p = base - b * kP + t;
  if (p >= kP) { p -= kP; ++b; }
  int i, j;
  decode_pair(p, i, j);

  const float3* __restrict__ x3 = (const float3*)x;

  __shared__ uint32_t slot[kItems * 4];
  unsigned long long masks[kItems];
  int gi[kItems], gj[kItems];
  bool fl[kItems];
  for (int k = 0; k < kItems; ++k) {
    int idx_i = b * kN + i;
    int idx_j = b * kN + j;
    float3 pi = x3[idx_i];
    float3 pj = x3[idx_j];
    float dx = pi.x - pj.x, dy = pi.y - pj.y, dz = pi.z - pj.z;
    bool f = dx * dx + dy * dy + dz * dz <= kCut2;
    fl[k] = f;
    gi[k] = idx_i;
    gj[k] = idx_j;
    masks[k] = __ballot(f);
    if (lane == 0) slot[k * 4 + wave] = (uint32_t)__popcll(masks[k]);
    if (k < kItems - 1) {
      // advance flat index by kBlock: walk rows (row i holds j in [i+1, N-1])
      j += kBlock;
      while (j >= kN) {
        int excess = j - kN;
        ++i;
        if (i >= kN - 1) { i = 0; ++b; }
        j = i + 1 + excess;
      }
    }
  }
  __syncthreads();
  if (t < 32) {  // parallel exclusive scan of the 32 (item,wave) counts
    uint32_t v = slot[t];
    uint32_t run = v;
    for (int off = 1; off < 32; off <<= 1) {
      uint32_t u = __shfl_up(run, off, 64);
      if (t >= off) run += u;
    }
    slot[t] = run - v;            // exclusive
    if (t == 31) counts[bid] = run;  // block total
  }
  __syncthreads();
  for (int k = 0; k < kItems; ++k) {
    if (fl[k]) {
      uint32_t pos = slot[k * 4 + wave] +
                     (uint32_t)__popcll(masks[k] & ((1ULL << lane) - 1ULL));
      if (pos < (uint32_t)kCap) stash[(size_t)bid * kCap + pos] = make_int2(gi[k], gj[k]);
    }
  }
}

__global__ __launch_bounds__(kBlock) void scan_kernel(const uint32_t* __restrict__ counts,
                                                      uint32_t* __restrict__ offsets) {
  __shared__ uint32_t s[kBlock];
  const int t = threadIdx.x;
  const uint4* c4 = (const uint4*)counts;  // [4096] incl. zero pad
  uint32_t loc[kScanPer];
  uint32_t sum = 0;
  for (int q = 0; q < 4; ++q) {
    uint4 c = c4[t * 4 + q];
    loc[q * 4 + 0] = sum; sum += c.x;
    loc[q * 4 + 1] = sum; sum += c.y;
    loc[q * 4 + 2] = sum; sum += c.z;
    loc[q * 4 + 3] = sum; sum += c.w;
  }
  s[t] = sum;
  __syncthreads();
  for (int off = 1; off < kBlock; off <<= 1) {
    uint32_t u = (t >= off) ? s[t - off] : 0u;
    __syncthreads();
    if (t >= off) s[t] += u;
    __syncthreads();
  }
  uint32_t base = (t == 0) ? 0u : s[t - 1];
  for (int k = 0; k < kScanPer; ++k) {
    int idx = t * kScanPer + k;
    if (idx < kNBlk) offsets[idx] = base + loc[k];
  }
}

__global__ __launch_bounds__(kBlock) void scatter_kernel(const float* __restrict__ x,
                                                         const uint32_t* __restrict__ counts,
                                                         const uint32_t* __restrict__ offsets,
                                                         const int2* __restrict__ stash,
                                                         int* __restrict__ out) {
  const int bid = blockIdx.x;
  const int t = threadIdx.x;
  const uint32_t cnt = counts[bid];
  if (cnt == 0) return;
  const uint32_t off = offsets[bid];
  if (cnt <= (uint32_t)kCap) {
    for (uint32_t e = t; e < cnt; e += kBlock) {
      int2 v = stash[(size_t)bid * kCap + e];
      out[off + e] = v.x;
      out[(size_t)kTotal + off + e] = v.y;
    }
    return;
  }
  // Overflow fallback (stash capacity exceeded): recompute this block's
  // edges with ballot ranks and write directly. Deterministic + exact.
  const int wave = t >> 6, lane = t & 63;
  const int base = bid * kChunk;
  const int bb0 = base / kP;
  const int p0 = base - bb0 * kP;
  __shared__ uint32_t slot[kItems * 4];
  unsigned long long masks[kItems];
  int gi[kItems], gj[kItems];
  bool fl[kItems];
  for (int k = 0; k < kItems; ++k) {
    int o = k * kBlock + t;
    int b = bb0, p = p0 + o;
    if (p >= kP) { p -= kP; ++b; }
    fl[k] = pair_test(x, b, p, gi[k], gj[k]);
    masks[k] = __ballot(fl[k]);
    if (lane == 0) slot[k * 4 + wave] = (uint32_t)__popcll(masks[k]);
  }
  __syncthreads();
  if (t == 0) {
    uint32_t run = 0;
    for (int s = 0; s < kItems * 4; ++s) {
      uint32_t c = slot[s];
      slot[s] = run;
      run += c;
    }
  }
  __syncthreads();
  for (int k = 0; k < kItems; ++k) {
    if (fl[k]) {
      uint32_t pos = off + slot[k * 4 + wave] +
                     (uint32_t)__popcll(masks[k] & ((1ULL << lane) - 1ULL));
      out[pos] = gi[k];
      out[(size_t)kTotal + pos] = gj[k];
    }
  }
}

extern "C" void kernel_launch(void* const* d_in, const int* in_sizes, int n_in,
                              void* d_out, int out_size, void* d_ws, size_t ws_size,
                              hipStream_t stream) {
  const float* x = (const float*)d_in[0];
  int* out = (int*)d_out;
  uint32_t* counts = (uint32_t*)d_ws;                 // [4096] (2 pad)
  uint32_t* offsets = counts + 4096;                  // [4094]
  int2* stash = (int2*)(offsets + 4096);              // [4094 * kCap]

  hipLaunchKernelGGL(pass1_kernel, dim3(kNBlk), dim3(kBlock), 0, stream, x, counts,
                     stash, out);
  hipLaunchKernelGGL(scan_kernel, dim3(1), dim3(kBlock), 0, stream, counts, offsets);
  hipLaunchKernelGGL(scatter_kernel, dim3(kNBlk), dim3(kBlock), 0, stream, x, counts,
                     offsets, stash, out);
}